// Round 3
// baseline (1147.610 us; speedup 1.0000x reference)
//
#include <hip/hip_runtime.h>
#include <math.h>

#define BATCH 64
#define N 1024
#define R 16                  // rows per stripe (one stripe per wave)
#define CHUNKS (N / R)        // 64 stripes per batch
#define NEG_INF (-3.402823466e+38f)
#define SCALE 144.26950408889634f   // (1/tau) * log2(e)  -> base-2 domain

__global__ __launch_bounds__(256) void zero_kernel(float* __restrict__ p, int n) {
    int i = blockIdx.x * 256 + threadIdx.x;
    if (i < n) p[i] = 0.0f;
}

// component select with compile-time c (folds to a register, never scratch)
#define ELEM(B, r, p, c) ((c) == 0 ? B[r][p].x : (c) == 1 ? B[r][p].y : (c) == 2 ? B[r][p].z : B[r][p].w)

// Issue all 16 dwordx4 loads for group g (rows g*4..g*4+3) into BUF.
#define LOADG(BUF, g)                                                          \
    {                                                                          \
        _Pragma("unroll")                                                      \
        for (int r_ = 0; r_ < 4; ++r_) {                                       \
            const float4* row4_ = (const float4*)(xb + (size_t)((g)*4 + r_) * N); \
            _Pragma("unroll")                                                  \
            for (int p_ = 0; p_ < 4; ++p_) BUF[r_][p_] = row4_[p_ * 64 + lane]; \
        }                                                                      \
    }

// Row-LSE for 4 rows + fold into running per-lane column partials.
#define COMPUTE(BUF, g)                                                        \
    {                                                                          \
        float v[4][16];                                                        \
        _Pragma("unroll")                                                      \
        for (int r_ = 0; r_ < 4; ++r_) {                                       \
            _Pragma("unroll")                                                  \
            for (int p_ = 0; p_ < 4; ++p_) {                                   \
                _Pragma("unroll")                                              \
                for (int c_ = 0; c_ < 4; ++c_)                                 \
                    v[r_][p_ * 4 + c_] = ELEM(BUF, r_, p_, c_) * SCALE - bvf[p_ * 4 + c_]; \
            }                                                                  \
        }                                                                      \
        float m_[4];                                                           \
        _Pragma("unroll")                                                      \
        for (int r_ = 0; r_ < 4; ++r_) {                                       \
            float lm = v[r_][0];                                               \
            _Pragma("unroll")                                                  \
            for (int e_ = 1; e_ < 16; ++e_) lm = fmaxf(lm, v[r_][e_]);         \
            m_[r_] = lm;                                                       \
        }                                                                      \
        _Pragma("unroll")                                                      \
        for (int off_ = 32; off_ >= 1; off_ >>= 1) {                           \
            _Pragma("unroll")                                                  \
            for (int r_ = 0; r_ < 4; ++r_)                                     \
                m_[r_] = fmaxf(m_[r_], __shfl_xor(m_[r_], off_, 64));          \
        }                                                                      \
        float s_[4];                                                           \
        _Pragma("unroll")                                                      \
        for (int r_ = 0; r_ < 4; ++r_) {                                       \
            float ls = 0.0f;                                                   \
            _Pragma("unroll")                                                  \
            for (int e_ = 0; e_ < 16; ++e_) ls += exp2f(v[r_][e_] - m_[r_]);   \
            s_[r_] = ls;                                                       \
        }                                                                      \
        _Pragma("unroll")                                                      \
        for (int off_ = 32; off_ >= 1; off_ >>= 1) {                           \
            _Pragma("unroll")                                                  \
            for (int r_ = 0; r_ < 4; ++r_)                                     \
                s_[r_] += __shfl_xor(s_[r_], off_, 64);                        \
        }                                                                      \
        float A_[4];                                                           \
        _Pragma("unroll")                                                      \
        for (int r_ = 0; r_ < 4; ++r_) A_[r_] = m_[r_] + __log2f(s_[r_]);      \
        if (lane == 0) {                                                       \
            avec[abase + (g)*4 + 0] = A_[0];                                   \
            avec[abase + (g)*4 + 1] = A_[1];                                   \
            avec[abase + (g)*4 + 2] = A_[2];                                   \
            avec[abase + (g)*4 + 3] = A_[3];                                   \
        }                                                                      \
        _Pragma("unroll")                                                      \
        for (int e_ = 0; e_ < 16; ++e_) {                                      \
            float t0 = v[0][e_] - A_[0];                                       \
            float t1 = v[1][e_] - A_[1];                                       \
            float t2 = v[2][e_] - A_[2];                                       \
            float t3 = v[3][e_] - A_[3];                                       \
            float m4 = fmaxf(fmaxf(t0, t1), fmaxf(t2, t3));                    \
            float s4 = exp2f(t0 - m4) + exp2f(t1 - m4) +                       \
                       exp2f(t2 - m4) + exp2f(t3 - m4);                        \
            float mn = fmaxf(mcol[e_], m4);                                    \
            scol[e_] = scol[e_] * exp2f(mcol[e_] - mn) + s4 * exp2f(m4 - mn);  \
            mcol[e_] = mn;                                                     \
        }                                                                      \
    }

// One stripe per wave: row-LSE (A) + column partials, x read exactly once,
// no LDS, no barriers, explicit double-buffered loads across 4-row groups.
__global__ __launch_bounds__(256, 2) void rowcol_kernel(
    const float* __restrict__ x, const float* __restrict__ bvec,
    float* __restrict__ avec, float* __restrict__ pm, float* __restrict__ ps)
{
    const int wave   = threadIdx.x >> 6;
    const int lane   = threadIdx.x & 63;
    const int stripe = blockIdx.x * 4 + wave;        // 0..4095
    const int batch  = stripe >> 6;                  // / CHUNKS
    const int chunk  = stripe & (CHUNKS - 1);
    const float* xb  = x + (size_t)batch * N * N + (size_t)chunk * R * N;
    const int abase  = batch * N + chunk * R;

    // B (base-2) for this lane's 16 columns: col = p*256 + lane*4 + c
    float bvf[16];
    {
        const float4* bv4 = (const float4*)(bvec + (size_t)batch * N);
        #pragma unroll
        for (int p = 0; p < 4; ++p) {
            float4 b = bv4[p * 64 + lane];
            bvf[p*4+0] = b.x; bvf[p*4+1] = b.y; bvf[p*4+2] = b.z; bvf[p*4+3] = b.w;
        }
    }

    float mcol[16], scol[16];
    #pragma unroll
    for (int e = 0; e < 16; ++e) { mcol[e] = NEG_INF; scol[e] = 0.0f; }

    float4 bufA[4][4], bufB[4][4];

    LOADG(bufA, 0)
    LOADG(bufB, 1)
    COMPUTE(bufA, 0)
    LOADG(bufA, 2)
    COMPUTE(bufB, 1)
    LOADG(bufB, 3)
    COMPUTE(bufA, 2)
    COMPUTE(bufB, 3)

    // write partials: pm holds max of (x*SCALE - A) = mcol + B, ps the sums
    const size_t pbase = ((size_t)batch * CHUNKS + chunk) * N;
    #pragma unroll
    for (int p = 0; p < 4; ++p) {
        float4 om = make_float4(mcol[p*4+0] + bvf[p*4+0], mcol[p*4+1] + bvf[p*4+1],
                                mcol[p*4+2] + bvf[p*4+2], mcol[p*4+3] + bvf[p*4+3]);
        float4 os = make_float4(scol[p*4+0], scol[p*4+1], scol[p*4+2], scol[p*4+3]);
        ((float4*)(pm + pbase))[p * 64 + lane] = om;
        ((float4*)(ps + pbase))[p * 64 + lane] = os;
    }
}

// Fold 64 stripe partials per column into B_j (base-2 LSE).
__global__ __launch_bounds__(256, 2) void combine_kernel(
    const float* __restrict__ pm, const float* __restrict__ ps,
    float* __restrict__ bvec)
{
    const int idx   = blockIdx.x * 256 + threadIdx.x;  // 0..BATCH*N-1
    const int batch = idx >> 10;
    const int j     = idx & (N - 1);
    const float* pmb = pm + (size_t)batch * CHUNKS * N + j;
    const float* psb = ps + (size_t)batch * CHUNKS * N + j;

    float mv[CHUNKS];
    #pragma unroll
    for (int c = 0; c < CHUNKS; ++c) mv[c] = pmb[(size_t)c * N];
    float M = NEG_INF;
    #pragma unroll
    for (int c = 0; c < CHUNKS; ++c) M = fmaxf(M, mv[c]);
    float s = 0.0f;
    #pragma unroll
    for (int c = 0; c < CHUNKS; ++c)
        s += psb[(size_t)c * N] * exp2f(mv[c] - M);
    bvec[idx] = M + __log2f(s);
}

// out = exp2(x*SCALE - A_i - B_j) + 1e-6
__global__ __launch_bounds__(256) void output_kernel(
    const float* __restrict__ x, const float* __restrict__ avec,
    const float* __restrict__ bvec, float* __restrict__ out)
{
    const int row   = blockIdx.x;      // batch*N + i
    const int batch = row >> 10;
    const float A   = avec[row];
    const int t     = threadIdx.x;

    float4 xv = ((const float4*)(x + (size_t)row * N))[t];
    float4 bv = ((const float4*)(bvec + (size_t)batch * N))[t];
    float4 o;
    o.x = exp2f(xv.x * SCALE - A - bv.x) + 1e-6f;
    o.y = exp2f(xv.y * SCALE - A - bv.y) + 1e-6f;
    o.z = exp2f(xv.z * SCALE - A - bv.z) + 1e-6f;
    o.w = exp2f(xv.w * SCALE - A - bv.w) + 1e-6f;
    ((float4*)(out + (size_t)row * N))[t] = o;
}

extern "C" void kernel_launch(void* const* d_in, const int* in_sizes, int n_in,
                              void* d_out, int out_size, void* d_ws, size_t ws_size,
                              hipStream_t stream) {
    const float* x = (const float*)d_in[0];
    float* out = (float*)d_out;
    char* ws = (char*)d_ws;

    float* avec = (float*)ws;                         // BATCH*N f32 (base-2)
    float* bvec = avec + (size_t)BATCH * N;           // BATCH*N f32 (base-2)
    const size_t small_bytes = 2ull * BATCH * N * sizeof(float);      // 512 KB
    const size_t pelems      = (size_t)BATCH * CHUNKS * N;            // 4.2M
    const size_t pbytes      = pelems * sizeof(float);                // ~16.8 MB

    float* pm;
    float* ps;
    if (ws_size >= small_bytes + 2 * pbytes) {
        pm = (float*)(ws + small_bytes);
        ps = pm + pelems;
    } else {
        // Park partials in d_out: fully consumed before output_kernel writes.
        pm = out;
        ps = out + pelems;
    }

    zero_kernel<<<(BATCH * N) / 256, 256, 0, stream>>>(bvec, BATCH * N);
    for (int iter = 0; iter < 5; ++iter) {
        rowcol_kernel<<<(BATCH * CHUNKS) / 4, 256, 0, stream>>>(x, bvec, avec, pm, ps);
        combine_kernel<<<(BATCH * N) / 256, 256, 0, stream>>>(pm, ps, bvec);
    }
    output_kernel<<<BATCH * N, 256, 0, stream>>>(x, avec, bvec, out);
}